// Round 10
// baseline (168.809 us; speedup 1.0000x reference)
//
#include <hip/hip_runtime.h>

typedef unsigned short u16;
typedef __attribute__((ext_vector_type(8))) short bf16x8;
typedef __attribute__((ext_vector_type(4))) float f32x4;
typedef __attribute__((ext_vector_type(16))) float f32x16;

#define MFMA16(A,B,C) __builtin_amdgcn_mfma_f32_16x16x32_bf16(A,B,C,0,0,0)
#define MFMA32(A,B,C) __builtin_amdgcn_mfma_f32_32x32x16_bf16(A,B,C,0,0,0)

#define B_ 4
#define C_ 256
#define N_ 2304
#define HEADS_ 8
#define DH_ 64
#define INNER_ 512
#define SCALE_LOG2E 14.426950408889634f   // 10 * log2(e); folded into Qn at k_qkv

__device__ __forceinline__ u16 f2bf(float f) {
    union { float f; unsigned int u; } v; v.f = f;
    unsigned int r = v.u + 0x7fffu + ((v.u >> 16) & 1u);
    return (u16)(r >> 16);
}
__device__ __forceinline__ float bf2f(u16 h) {
    union { unsigned int u; float f; } v; v.u = ((unsigned int)h) << 16;
    return v.f;
}
// pack two floats to bf16x2 in ONE VALU op (RNE, same class as f2bf)
__device__ __forceinline__ unsigned int cvtpk(float a, float b) {
    unsigned int r;
    asm("v_cvt_pk_bf16_f32 %0, %1, %2" : "=v"(r) : "v"(a), "v"(b));
    return r;
}
// swap a's upper 32 lanes with b's lower 32 lanes (in place)
__device__ __forceinline__ void pl32swap(unsigned &a, unsigned &b) {
    asm volatile("v_permlane32_swap_b32 %0, %1" : "+v"(a), "+v"(b));
}
// raw 2^x: scores bounded to |x| <= ~15.3, OCML denorm fixup is dead code.
__device__ __forceinline__ float fexp2(float x) {
    float r;
    asm("v_exp_f32 %0, %1" : "=v"(r) : "v"(x));
    return r;
}
// accumulate 2 bf16 packed in u into lo/hi f32 sums
__device__ __forceinline__ void bfacc(unsigned u, float &lo, float &hi) {
    union { unsigned x; float f; } a, c;
    a.x = u << 16; c.x = u & 0xffff0000u;
    lo += a.f; hi += c.f;
}

// ---------------- Kernel P: fused prep (transpose x + convert weights) ----------------
__global__ __launch_bounds__(256) void k_prep(const float* __restrict__ x,
                                              u16* __restrict__ xT,
                                              const float* __restrict__ w_qkv,
                                              u16* __restrict__ wqb,
                                              const float* __restrict__ w_out,
                                              u16* __restrict__ wob) {
    __shared__ float tile[64][65];
    int idx = blockIdx.x;
    int t = threadIdx.x;
    if (idx < 576) {
        int b = idx / 144, rem = idx % 144;
        int n0 = (rem >> 2) * 64, c0 = (rem & 3) * 64;
        const float* xb = x + (size_t)b * C_ * N_;
        u16* xTb = xT + (size_t)b * N_ * C_;
        int r = t >> 4;
        int q4 = (t & 15) * 4;
#pragma unroll
        for (int pass = 0; pass < 4; ++pass) {
            int c = r + pass * 16;
            float4 v = *(const float4*)(xb + (size_t)(c0 + c) * N_ + n0 + q4);
            tile[c][q4+0] = v.x; tile[c][q4+1] = v.y; tile[c][q4+2] = v.z; tile[c][q4+3] = v.w;
        }
        __syncthreads();
#pragma unroll
        for (int pass = 0; pass < 4; ++pass) {
            int n = r + pass * 16;
            ushort4 o;
            o.x = f2bf(tile[q4+0][n]); o.y = f2bf(tile[q4+1][n]);
            o.z = f2bf(tile[q4+2][n]); o.w = f2bf(tile[q4+3][n]);
            *(ushort4*)(xTb + (size_t)(n0 + n) * C_ + c0 + q4) = o;
        }
    } else if (idx < 960) {
        int i = (idx - 576) * 256 + t;
        float4 v = ((const float4*)w_qkv)[i];
        ushort4 o;
        o.x = f2bf(v.x); o.y = f2bf(v.y); o.z = f2bf(v.z); o.w = f2bf(v.w);
        ((ushort4*)wqb)[i] = o;
    } else {
        int i = (idx - 960) * 256 + t;
        float4 v = ((const float4*)w_out)[i];
        ushort4 o;
        o.x = f2bf(v.x); o.y = f2bf(v.y); o.z = f2bf(v.z); o.w = f2bf(v.w);
        ((ushort4*)wob)[i] = o;
    }
}

// ---------------- Kernel 1: QKV GEMM (LDS-staged) + l2norm(q,k) ----------------
__global__ __launch_bounds__(256) void k_qkv(const u16* __restrict__ w_qkv,
                                             const u16* __restrict__ xT,
                                             u16* __restrict__ Qn,
                                             u16* __restrict__ Kn,
                                             u16* __restrict__ Vt) {
    __shared__ __align__(16) u16 Wt[64][264];
    __shared__ __align__(16) u16 Xt[64][264];
    int mt = blockIdx.x, nt = blockIdx.y, b = blockIdx.z;
    int tid = threadIdx.x;
    int wv = tid >> 6, lane = tid & 63;
    int col = lane & 15, quad = lane >> 4;
    int o0 = mt * 64;
    const u16* wtile = w_qkv + (size_t)o0 * C_;
    const u16* xtile = xT + ((size_t)b * N_ + nt*64) * C_;
#pragma unroll
    for (int p = 0; p < 8; ++p) {
        int c = p * 256 + tid;
        int row = c >> 5, seg = c & 31;
        *(uint4*)(&Wt[row][seg*8]) = *(const uint4*)(wtile + (size_t)row * C_ + seg*8);
        *(uint4*)(&Xt[row][seg*8]) = *(const uint4*)(xtile + (size_t)row * C_ + seg*8);
    }
    __syncthreads();
    f32x4 z = {0.f, 0.f, 0.f, 0.f};
    f32x4 acc[4]; acc[0]=z; acc[1]=z; acc[2]=z; acc[3]=z;
#pragma unroll
    for (int ks = 0; ks < 8; ++ks) {
        bf16x8 bfrag = *(const bf16x8*)(&Xt[wv*16 + col][ks*32 + quad*8]);
#pragma unroll
        for (int mb = 0; mb < 4; ++mb) {
            bf16x8 afrag = *(const bf16x8*)(&Wt[mb*16 + col][ks*32 + quad*8]);
            acc[mb] = MFMA16(afrag, bfrag, acc[mb]);
        }
    }
    int n = nt * 64 + wv * 16 + col;
    int which = mt >> 3, h = mt & 7;
    if (which < 2) {
        float s = 0.f;
#pragma unroll
        for (int mb = 0; mb < 4; ++mb)
#pragma unroll
            for (int r = 0; r < 4; ++r) s += acc[mb][r] * acc[mb][r];
        s += __shfl_xor(s, 16);
        s += __shfl_xor(s, 32);
        float inv = 1.f / fmaxf(sqrtf(s), 1e-12f);
        if (which == 0) inv *= SCALE_LOG2E;   // fold softmax scale into Q
        u16* dst = (which == 0 ? Qn : Kn) + (((size_t)b * HEADS_ + h) * N_ + n) * DH_;
#pragma unroll
        for (int mb = 0; mb < 4; ++mb) {
            uint2 o;
            o.x = cvtpk(acc[mb][0] * inv, acc[mb][1] * inv);
            o.y = cvtpk(acc[mb][2] * inv, acc[mb][3] * inv);
            *(uint2*)(dst + mb*16 + quad*4) = o;
        }
    } else {
        u16* dst = Vt + ((size_t)b * HEADS_ + h) * (size_t)DH_ * N_;
#pragma unroll
        for (int mb = 0; mb < 4; ++mb)
#pragma unroll
            for (int r = 0; r < 4; ++r)
                dst[(size_t)(mb*16 + quad*4 + r) * N_ + n] = f2bf(acc[mb][r]);
    }
}

// store one 32-d block of O (already cvt/swap'd to contiguous groups)
__device__ __forceinline__ void store_o32(const f32x16 O, u16* dst, int hi) {
    unsigned c0 = cvtpk(O[0], O[1]),  c1 = cvtpk(O[2], O[3]);
    unsigned c2 = cvtpk(O[4], O[5]),  c3 = cvtpk(O[6], O[7]);
    unsigned c4 = cvtpk(O[8], O[9]),  c5 = cvtpk(O[10], O[11]);
    unsigned c6 = cvtpk(O[12], O[13]), c7 = cvtpk(O[14], O[15]);
    pl32swap(c0, c2); pl32swap(c1, c3);
    pl32swap(c4, c6); pl32swap(c5, c7);
    uint4 w0; w0.x = c0; w0.y = c1; w0.z = c2; w0.w = c3;
    uint4 w1; w1.x = c4; w1.y = c5; w1.z = c6; w1.w = c7;
    *(uint4*)(dst + hi*8)      = w0;
    *(uint4*)(dst + 16 + hi*8) = w1;
}

// build the two P bf16 B-frags for one 32-key half from 16 exp'd scores
#define SM_PACK(S, PF0, PF1, LSUM)                                              \
    {                                                                           \
        _Pragma("unroll")                                                       \
        for (int i = 0; i < 16; ++i) S[i] = fexp2(S[i]);                        \
        LSUM += ( ((S[0]+S[1])+(S[2]+S[3])) + ((S[4]+S[5])+(S[6]+S[7])) )       \
              + ( ((S[8]+S[9])+(S[10]+S[11])) + ((S[12]+S[13])+(S[14]+S[15])) );\
        unsigned c0 = cvtpk(S[0], S[1]),  c1 = cvtpk(S[2], S[3]);               \
        unsigned c2 = cvtpk(S[4], S[5]),  c3 = cvtpk(S[6], S[7]);               \
        unsigned c4 = cvtpk(S[8], S[9]),  c5 = cvtpk(S[10], S[11]);             \
        unsigned c6 = cvtpk(S[12], S[13]), c7 = cvtpk(S[14], S[15]);            \
        pl32swap(c0, c2); pl32swap(c1, c3);                                     \
        pl32swap(c4, c6); pl32swap(c5, c7);                                     \
        PF0.u[0] = c0; PF0.u[1] = c1; PF0.u[2] = c2; PF0.u[3] = c3;             \
        PF1.u[0] = c4; PF1.u[1] = c5; PF1.u[2] = c6; PF1.u[3] = c7;             \
    }

// ---------------- Kernel 2a: flash attention, 2-way K-split, 32x32 swapped-QK ----
// Double-buffered K/V LDS, one barrier/iter. Grid 1152 = 2 ksplit x 18 qt x 32.
// PV uses 4 INDEPENDENT accumulator chains (a/b per O-half) to break the
// cross-tile serial MFMA backbone (latency-bound per R9 analysis); merged once
// at the epilogue. ksplit=2 halves partial-write traffic and epilogue count.
__global__ __launch_bounds__(256) void k_attn_split(const u16* __restrict__ Qn,
                                                    const u16* __restrict__ Kn,
                                                    const u16* __restrict__ Vt,
                                                    u16* __restrict__ Opb,
                                                    float* __restrict__ lp) {
    __shared__ __align__(16) u16 Kt[2][64][72];
    __shared__ __align__(16) u16 Vtl[2][64][72];
    int head_lin = blockIdx.x & 31;                 // head -> XCD pinning
    int rest = blockIdx.x >> 5;                     // 0..35
    int qt = rest % 18;
    int ksplit = rest / 18;                         // 0..1
    int b = head_lin >> 3, h = head_lin & 7;
    int tid = threadIdx.x;
    int wv = tid >> 6, lane = tid & 63;
    int q32 = lane & 31, hi = lane >> 5;
    size_t head = (size_t)b * HEADS_ + h;
    const u16* Qh = Qn + head * (size_t)N_ * DH_;
    const u16* Kh = Kn + head * (size_t)N_ * DH_ + (size_t)ksplit * 1152 * DH_;
    const u16* Vh = Vt + head * (size_t)DH_ * N_;
    int q0 = qt * 128 + wv * 32;
    bf16x8 qf[4];
#pragma unroll
    for (int ds = 0; ds < 4; ++ds)
        qf[ds] = *(const bf16x8*)(Qh + (size_t)(q0 + q32) * DH_ + ds*16 + hi*8);
    // opaque zero vector: stays live across the loop, never re-materialized
    float z0 = 0.f;
    asm volatile("" : "+v"(z0));
    f32x16 zv;
#pragma unroll
    for (int i = 0; i < 16; ++i) zv[i] = z0;
    f32x16 accO0a = zv, accO0b = zv, accO1a = zv, accO1b = zv;
    float lsum = 0.f;
    int srow = tid >> 3, sseg = tid & 7;
    const u16* ksrc0 = Kh + (size_t)tid * 8;
    const u16* vsrc0 = Vh + (size_t)srow * N_ + ksplit * 1152 + sseg * 8;

    uint4 k0 = *(const uint4*)(ksrc0);
    uint4 k1 = *(const uint4*)(ksrc0 + 2048);
    uint4 v0 = *(const uint4*)(vsrc0);
    uint4 v1 = *(const uint4*)(vsrc0 + (size_t)32 * N_);
    *(uint4*)(&Kt[0][srow][sseg*8])       = k0;
    *(uint4*)(&Kt[0][32 + srow][sseg*8])  = k1;
    *(uint4*)(&Vtl[0][srow][sseg*8])      = v0;
    *(uint4*)(&Vtl[0][32 + srow][sseg*8]) = v1;
    const u16* kp = ksrc0 + 4096;                   // next K-tile (8KB stride)
    const u16* vp = vsrc0 + 64;                     // next V-tile (64-key stride)
    int cur = 0;

    for (int kt = 0; kt < 18; ++kt) {
        __syncthreads();
        // prefetch next tile (last iter over-reads into workspace; dead data)
        k0 = *(const uint4*)(kp);
        k1 = *(const uint4*)(kp + 2048);
        v0 = *(const uint4*)(vp);
        v1 = *(const uint4*)(vp + (size_t)32 * N_);
        kp += 4096; vp += 64;
        const u16* kb0 = &Kt[cur][q32][hi*8];
        const u16* kb1 = kb0 + 32*72;
        const u16* vb0 = &Vtl[cur][q32][hi*8];
        const u16* vb1 = vb0 + 32*72;
        // ---- QK^T both key-halves (MFMA cluster) ----
        f32x16 s0, s1;
        __builtin_amdgcn_s_setprio(1);
        s0 = MFMA32(*(const bf16x8*)(kb0),      qf[0], zv);
        s0 = MFMA32(*(const bf16x8*)(kb0 + 16), qf[1], s0);
        s0 = MFMA32(*(const bf16x8*)(kb0 + 32), qf[2], s0);
        s0 = MFMA32(*(const bf16x8*)(kb0 + 48), qf[3], s0);
        s1 = MFMA32(*(const bf16x8*)(kb1),      qf[0], zv);
        s1 = MFMA32(*(const bf16x8*)(kb1 + 16), qf[1], s1);
        s1 = MFMA32(*(const bf16x8*)(kb1 + 32), qf[2], s1);
        s1 = MFMA32(*(const bf16x8*)(kb1 + 48), qf[3], s1);
        __builtin_amdgcn_s_setprio(0);
        // ---- softmax half 0 (VALU) ----
        union { unsigned u[4]; bf16x8 v; } pfA, pfB, pfC, pfD;
        SM_PACK(s0, pfA, pfB, lsum)
        // ---- PV half 0 (keys 0..31): independent chains a/b ----
        __builtin_amdgcn_s_setprio(1);
        accO0a = MFMA32(*(const bf16x8*)(vb0),      pfA.v, accO0a);
        accO1a = MFMA32(*(const bf16x8*)(vb1),      pfA.v, accO1a);
        accO0b = MFMA32(*(const bf16x8*)(vb0 + 16), pfB.v, accO0b);
        accO1b = MFMA32(*(const bf16x8*)(vb1 + 16), pfB.v, accO1b);
        __builtin_amdgcn_s_setprio(0);
        // ---- softmax half 1 (VALU) ----
        SM_PACK(s1, pfC, pfD, lsum)
        // ---- PV half 1 (keys 32..63) ----
        __builtin_amdgcn_s_setprio(1);
        accO0a = MFMA32(*(const bf16x8*)(vb0 + 32), pfC.v, accO0a);
        accO1a = MFMA32(*(const bf16x8*)(vb1 + 32), pfC.v, accO1a);
        accO0b = MFMA32(*(const bf16x8*)(vb0 + 48), pfD.v, accO0b);
        accO1b = MFMA32(*(const bf16x8*)(vb1 + 48), pfD.v, accO1b);
        __builtin_amdgcn_s_setprio(0);
        // ---- stage next tile into the other buffer ----
        {
            u16 (*Ktn_)[72] = Kt[cur ^ 1];
            u16 (*Vtn_)[72] = Vtl[cur ^ 1];
            *(uint4*)(&Ktn_[srow][sseg*8])      = k0;
            *(uint4*)(&Ktn_[32 + srow][sseg*8]) = k1;
            *(uint4*)(&Vtn_[srow][sseg*8])      = v0;
            *(uint4*)(&Vtn_[32 + srow][sseg*8]) = v1;
        }
        cur ^= 1;
    }
    lsum += __shfl_xor(lsum, 32);
    f32x16 accO0 = accO0a + accO0b;
    f32x16 accO1 = accO1a + accO1b;
    u16* dst = Opb + (((size_t)ksplit * B_ + b) * N_ + q0 + q32) * INNER_ + h * DH_;
    store_o32(accO0, dst, hi);
    store_o32(accO1, dst + 32, hi);
    if (hi == 0) {
        size_t lbase = (((size_t)ksplit * B_ + b) * HEADS_ + h) * N_;
        lp[lbase + q0 + q32] = lsum;
    }
}

// ---------------- Kernel 2c: combine 2 bf16 partials -> AO bf16 ----------------
// XCD-pinned (blockIdx&31 matches producer). uint4 (8 bf16) per thread.
__global__ __launch_bounds__(256) void k_comb(const u16* __restrict__ Opb,
                                              const float* __restrict__ lp,
                                              u16* __restrict__ AO) {
    int head_lin = blockIdx.x & 31;               // same pinning as attn
    int chunk = blockIdx.x >> 5;                  // 0..71
    int b = head_lin >> 3, h = head_lin & 7;
    int j = chunk * 256 + threadIdx.x;            // 0..18431 per (b,h)
    int n = j >> 3;                               // 0..2303
    int i8 = j & 7;                               // uint4 within 64-d head slice
    size_t g = ((size_t)b * N_ + n) * 64 + h * 8 + i8;   // uint4 units
    float l = 0.f;
#pragma unroll
    for (int s = 0; s < 2; ++s)
        l += lp[(((size_t)s * B_ + b) * HEADS_ + h) * N_ + n];
    float s0=0.f,s1=0.f,s2=0.f,s3=0.f,s4=0.f,s5=0.f,s6=0.f,s7=0.f;
#pragma unroll
    for (int s = 0; s < 2; ++s) {
        uint4 p = ((const uint4*)Opb)[g + (size_t)s * 589824];
        bfacc(p.x, s0, s1); bfacc(p.y, s2, s3);
        bfacc(p.z, s4, s5); bfacc(p.w, s6, s7);
    }
    float inv = 1.f / l;
    uint4 o;
    o.x = cvtpk(s0*inv, s1*inv); o.y = cvtpk(s2*inv, s3*inv);
    o.z = cvtpk(s4*inv, s5*inv); o.w = cvtpk(s6*inv, s7*inv);
    ((uint4*)AO)[g] = o;
}

// ---------------- Kernel 2b: fallback single-pass attention ----------------
__global__ __launch_bounds__(256) void k_attn(const u16* __restrict__ Qn,
                                              const u16* __restrict__ Kn,
                                              const u16* __restrict__ Vt,
                                              u16* __restrict__ AO) {
    __shared__ __align__(16) u16 Kt[64][72];
    __shared__ __align__(16) u16 Vtl[64][72];
    __shared__ __align__(16) u16 plds[4][32][72];
    int head_lin = blockIdx.x & 31;
    int qt = blockIdx.x >> 5;
    int b = head_lin >> 3, h = head_lin & 7;
    int tid = threadIdx.x;
    int wv = tid >> 6, lane = tid & 63;
    int col = lane & 15, quad = lane >> 4;
    size_t head = (size_t)b * HEADS_ + h;
    const u16* Qh = Qn + head * (size_t)N_ * DH_;
    const u16* Kh = Kn + head * (size_t)N_ * DH_;
    const u16* Vh = Vt + head * (size_t)DH_ * N_;
    int q0 = qt * 128 + wv * 32;
    bf16x8 qfA0 = *(const bf16x8*)(Qh + (size_t)(q0 + col) * DH_ + quad*8);
    bf16x8 qfA1 = *(const bf16x8*)(Qh + (size_t)(q0 + col) * DH_ + 32 + quad*8);
    bf16x8 qfB0 = *(const bf16x8*)(Qh + (size_t)(q0 + 16 + col) * DH_ + quad*8);
    bf16x8 qfB1 = *(const bf16x8*)(Qh + (size_t)(q0 + 16 + col) * DH_ + 32 + quad*8);
    f32x4 z = {0.f, 0.f, 0.f, 0.f};
    f32x4 OA[4], OB[4];
#pragma unroll
    for (int i = 0; i < 4; ++i) { OA[i] = z; OB[i] = z; }
    float lA = 0.f, lB = 0.f;
    int srow = tid >> 3, sseg = tid & 7;
    const u16* ksrc0 = Kh + (size_t)tid * 8;
    const u16* vsrc0 = Vh + (size_t)srow * N_ + sseg * 8;
    uint4 k0 = *(const uint4*)(ksrc0);
    uint4 k1 = *(const uint4*)(ksrc0 + 2048);
    uint4 v0 = *(const uint4*)(vsrc0);
    uint4 v1 = *(const uint4*)(vsrc0 + (size_t)32 * N_);
    for (int kt = 0; kt < N_/64; ++kt) {
        *(uint4*)(&Kt[srow][sseg*8])      = k0;
        *(uint4*)(&Kt[32 + srow][sseg*8]) = k1;
        *(uint4*)(&Vtl[srow][sseg*8])      = v0;
        *(uint4*)(&Vtl[32 + srow][sseg*8]) = v1;
        __syncthreads();
        int ktn = kt + 1 < N_/64 ? kt + 1 : kt;
        k0 = *(const uint4*)(ksrc0 + (size_t)ktn * 4096);
        k1 = *(const uint4*)(ksrc0 + (size_t)ktn * 4096 + 2048);
        v0 = *(const uint4*)(vsrc0 + ktn * 64);
        v1 = *(const uint4*)(vsrc0 + (size_t)32 * N_ + ktn * 64);
        float rsA = 0.f, rsB = 0.f;
#pragma unroll
        for (int nb = 0; nb < 4; ++nb) {
            bf16x8 kf0 = *(const bf16x8*)(&Kt[nb*16 + col][quad*8]);
            bf16x8 kf1 = *(const bf16x8*)(&Kt[nb*16 + col][32 + quad*8]);
            f32x4 a = MFMA16(kf0, qfA0, z);
            a = MFMA16(kf1, qfA1, a);
            f32x4 c = MFMA16(kf0, qfB0, z);
            c = MFMA16(kf1, qfB1, c);
            float a0 = fexp2(a[0]);
            float a1 = fexp2(a[1]);
            float a2 = fexp2(a[2]);
            float a3 = fexp2(a[3]);
            float c0 = fexp2(c[0]);
            float c1 = fexp2(c[1]);
            float c2 = fexp2(c[2]);
            float c3 = fexp2(c[3]);
            rsA += (a0 + a1) + (a2 + a3);
            rsB += (c0 + c1) + (c2 + c3);
            uint2 wA, wB;
            wA.x = cvtpk(a0, a1); wA.y = cvtpk(a2, a3);
            wB.x = cvtpk(c0, c1); wB.y = cvtpk(c2, c3);
            *(uint2*)(&plds[wv][col][nb*16 + quad*4]) = wA;
            *(uint2*)(&plds[wv][16 + col][nb*16 + quad*4]) = wB;
        }
        lA += rsA; lB += rsB;
        __asm__ volatile("" ::: "memory");
#pragma unroll
        for (int ks = 0; ks < 2; ++ks) {
            bf16x8 pfA = *(const bf16x8*)(&plds[wv][col][ks*32 + quad*8]);
            bf16x8 pfB = *(const bf16x8*)(&plds[wv][16 + col][ks*32 + quad*8]);
#pragma unroll
            for (int nb = 0; nb < 4; ++nb) {
                bf16x8 vf = *(const bf16x8*)(&Vtl[nb*16 + col][ks*32 + quad*8]);
                OA[nb] = MFMA16(vf, pfA, OA[nb]);
                OB[nb] = MFMA16(vf, pfB, OB[nb]);
            }
        }
        __asm__ volatile("" ::: "memory");
        __syncthreads();
    }
    lA += __shfl_xor(lA, 16); lA += __shfl_xor(lA, 32);
    lB += __shfl_xor(lB, 16); lB += __shfl_xor(lB, 32);
    float linvA = 1.f / lA, linvB = 1.f / lB;
    u16* dstA = AO + ((size_t)b * N_ + q0 + col) * INNER_ + h * DH_;
    u16* dstB = AO + ((size_t)b * N_ + q0 + 16 + col) * INNER_ + h * DH_;
#pragma unroll
    for (int nb = 0; nb < 4; ++nb) {
        uint2 wA, wB;
        wA.x = cvtpk(OA[nb][0] * linvA, OA[nb][1] * linvA);
        wA.y = cvtpk(OA[nb][2] * linvA, OA[nb][3] * linvA);
        wB.x = cvtpk(OB[nb][0] * linvB, OB[nb][1] * linvB);
        wB.y = cvtpk(OB[nb][2] * linvB, OB[nb][3] * linvB);
        *(uint2*)(dstA + nb*16 + quad*4) = wA;
        *(uint2*)(dstB + nb*16 + quad*4) = wB;
    }
}

// ---------------- Kernel 3: output projection (LDS-staged) + bias ----------------
__global__ __launch_bounds__(256) void k_proj(const u16* __restrict__ w_out,
                                              const float* __restrict__ b_out,
                                              const u16* __restrict__ AO,
                                              float* __restrict__ out) {
    __shared__ __align__(16) u16 Wt[64][264];
    __shared__ __align__(16) u16 At[64][264];
    int mt = blockIdx.x, nt = blockIdx.y, b = blockIdx.z;
    int tid = threadIdx.x;
    int wv = tid >> 6, lane = tid & 63;
    int col = lane & 15, quad = lane >> 4;
    int o0b = mt * 64;
    const u16* wtile = w_out + (size_t)o0b * INNER_;
    const u16* atile = AO + ((size_t)b * N_ + nt*64) * INNER_;
    f32x4 z = {0.f, 0.f, 0.f, 0.f};
    f32x4 acc[4]; acc[0]=z; acc[1]=z; acc[2]=z; acc[3]=z;
#pragma unroll
    for (int half = 0; half < 2; ++half) {
        if (half) __syncthreads();
#pragma unroll
        for (int p = 0; p < 8; ++p) {
            int c = p * 256 + tid;
            int row = c >> 5, seg = c & 31;
            *(uint4*)(&Wt[row][seg*8]) =
                *(const uint4*)(wtile + (size_t)row * INNER_ + half*256 + seg*8);
            *(uint4*)(&At[row][seg*8]) =
                *(const uint4*)(atile + (size_t)row * INNER_ + half*256 + seg*8);
        }
        __syncthreads();
#pragma unroll
        for (int ks = 0; ks < 8; ++ks) {
            bf16x8 af = *(const bf16x8*)(&Wt[wv*16 + col][ks*32 + quad*8]);
#pragma unroll
            for (int nb = 0; nb < 4; ++nb) {
                bf16x8 bfv = *(const bf16x8*)(&At[nb*16 + col][ks*32 + quad*8]);
                acc[nb] = MFMA16(af, bfv, acc[nb]);
            }
        }
    }
    int o0 = o0b + wv * 16;
    float bias[4];
#pragma unroll
    for (int r = 0; r < 4; ++r) bias[r] = b_out[o0 + quad*4 + r];
    float* dst = out + ((size_t)b * C_ + o0) * N_ + nt*64;
#pragma unroll
    for (int nb = 0; nb < 4; ++nb)
#pragma unroll
        for (int r = 0; r < 4; ++r)
            dst[(size_t)(quad*4 + r) * N_ + nb*16 + col] = acc[nb][r] + bias[r];
}

// ---------------- launch ----------------
extern "C" void kernel_launch(void* const* d_in, const int* in_sizes, int n_in,
                              void* d_out, int out_size, void* d_ws, size_t ws_size,
                              hipStream_t stream) {
    const float* x     = (const float*)d_in[0];
    const float* w_qkv = (const float*)d_in[1];
    const float* w_out = (const float*)d_in[2];
    const float* b_out = (const float*)d_in[3];
    float* out = (float*)d_out;

    char* ws = (char*)d_ws;
    u16* xT  = (u16*)(ws);                 // dead after k_qkv; lp reuses this region
    u16* Qn  = (u16*)(ws + 4718592);
    u16* Kn  = (u16*)(ws + 14155776);
    u16* Vt  = (u16*)(ws + 23592960);
    u16* AO  = (u16*)(ws + 33030144);
    u16* wqb = (u16*)(ws + 42467328);
    u16* wob = (u16*)(ws + 43253760);
    u16* Opb = (u16*)(ws + 43515904);      // 2 x 9,437,184 B bf16 partials
    float* lp = (float*)(ws + 1179648);    // 2 x 294,912 B f32 row sums (dead xT region)
    const size_t need = 81854464;

    hipLaunchKernelGGL(k_prep, dim3(1088), dim3(256), 0, stream, x, xT, w_qkv, wqb, w_out, wob);
    hipLaunchKernelGGL(k_qkv,  dim3(24, N_/64, B_), dim3(256), 0, stream, wqb, xT, Qn, Kn, Vt);
    if (ws_size >= need) {
        hipLaunchKernelGGL(k_attn_split, dim3(1152), dim3(256), 0, stream, Qn, Kn, Vt, Opb, lp);
        hipLaunchKernelGGL(k_comb, dim3(2304), dim3(256), 0, stream, Opb, lp, AO);
    } else {
        hipLaunchKernelGGL(k_attn, dim3((N_/128) * 32), dim3(256), 0, stream, Qn, Kn, Vt, AO);
    }
    hipLaunchKernelGGL(k_proj, dim3(C_/64, N_/64, B_), dim3(256), 0, stream, wob, b_out, AO, out);
}

// Round 11
// 164.794 us; speedup vs baseline: 1.0244x; 1.0244x over previous
//
#include <hip/hip_runtime.h>

typedef unsigned short u16;
typedef __attribute__((ext_vector_type(8))) short bf16x8;
typedef __attribute__((ext_vector_type(4))) float f32x4;
typedef __attribute__((ext_vector_type(16))) float f32x16;

#define MFMA16(A,B,C) __builtin_amdgcn_mfma_f32_16x16x32_bf16(A,B,C,0,0,0)
#define MFMA32(A,B,C) __builtin_amdgcn_mfma_f32_32x32x16_bf16(A,B,C,0,0,0)

#define B_ 4
#define C_ 256
#define N_ 2304
#define HEADS_ 8
#define DH_ 64
#define INNER_ 512
#define SCALE_LOG2E 14.426950408889634f   // 10 * log2(e); folded into Qn at k_qkv

__device__ __forceinline__ u16 f2bf(float f) {
    union { float f; unsigned int u; } v; v.f = f;
    unsigned int r = v.u + 0x7fffu + ((v.u >> 16) & 1u);
    return (u16)(r >> 16);
}
__device__ __forceinline__ float bf2f(u16 h) {
    union { unsigned int u; float f; } v; v.u = ((unsigned int)h) << 16;
    return v.f;
}
// pack two floats to bf16x2 in ONE VALU op (RNE, same class as f2bf)
__device__ __forceinline__ unsigned int cvtpk(float a, float b) {
    unsigned int r;
    asm("v_cvt_pk_bf16_f32 %0, %1, %2" : "=v"(r) : "v"(a), "v"(b));
    return r;
}
// swap a's upper 32 lanes with b's lower 32 lanes (in place)
__device__ __forceinline__ void pl32swap(unsigned &a, unsigned &b) {
    asm volatile("v_permlane32_swap_b32 %0, %1" : "+v"(a), "+v"(b));
}
// raw 2^x: scores bounded to |x| <= ~14.6, OCML denorm fixup is dead code.
__device__ __forceinline__ float fexp2(float x) {
    float r;
    asm("v_exp_f32 %0, %1" : "=v"(r) : "v"(x));
    return r;
}
// accumulate 2 bf16 packed in u into lo/hi f32 sums
__device__ __forceinline__ void bfacc(unsigned u, float &lo, float &hi) {
    union { unsigned x; float f; } a, c;
    a.x = u << 16; c.x = u & 0xffff0000u;
    lo += a.f; hi += c.f;
}

// ---------------- Kernel P: fused prep (transpose x + convert weights) ----------------
__global__ __launch_bounds__(256) void k_prep(const float* __restrict__ x,
                                              u16* __restrict__ xT,
                                              const float* __restrict__ w_qkv,
                                              u16* __restrict__ wqb,
                                              const float* __restrict__ w_out,
                                              u16* __restrict__ wob) {
    __shared__ float tile[64][65];
    int idx = blockIdx.x;
    int t = threadIdx.x;
    if (idx < 576) {
        int b = idx / 144, rem = idx % 144;
        int n0 = (rem >> 2) * 64, c0 = (rem & 3) * 64;
        const float* xb = x + (size_t)b * C_ * N_;
        u16* xTb = xT + (size_t)b * N_ * C_;
        int r = t >> 4;
        int q4 = (t & 15) * 4;
#pragma unroll
        for (int pass = 0; pass < 4; ++pass) {
            int c = r + pass * 16;
            float4 v = *(const float4*)(xb + (size_t)(c0 + c) * N_ + n0 + q4);
            tile[c][q4+0] = v.x; tile[c][q4+1] = v.y; tile[c][q4+2] = v.z; tile[c][q4+3] = v.w;
        }
        __syncthreads();
#pragma unroll
        for (int pass = 0; pass < 4; ++pass) {
            int n = r + pass * 16;
            ushort4 o;
            o.x = f2bf(tile[q4+0][n]); o.y = f2bf(tile[q4+1][n]);
            o.z = f2bf(tile[q4+2][n]); o.w = f2bf(tile[q4+3][n]);
            *(ushort4*)(xTb + (size_t)(n0 + n) * C_ + c0 + q4) = o;
        }
    } else if (idx < 960) {
        int i = (idx - 576) * 256 + t;
        float4 v = ((const float4*)w_qkv)[i];
        ushort4 o;
        o.x = f2bf(v.x); o.y = f2bf(v.y); o.z = f2bf(v.z); o.w = f2bf(v.w);
        ((ushort4*)wqb)[i] = o;
    } else {
        int i = (idx - 960) * 256 + t;
        float4 v = ((const float4*)w_out)[i];
        ushort4 o;
        o.x = f2bf(v.x); o.y = f2bf(v.y); o.z = f2bf(v.z); o.w = f2bf(v.w);
        ((ushort4*)wob)[i] = o;
    }
}

// compute one 64x64 tile from staged Wt/Xt and run the per-mt epilogue
__device__ __forceinline__ void qkv_tile(const u16 (*__restrict__ Wt)[264],
                                         const u16 (*__restrict__ Xt)[264],
                                         int wv, int col, int quad, int n, int b, int mt,
                                         u16* __restrict__ Qn, u16* __restrict__ Kn,
                                         u16* __restrict__ Vt) {
    f32x4 z = {0.f, 0.f, 0.f, 0.f};
    f32x4 acc[4]; acc[0]=z; acc[1]=z; acc[2]=z; acc[3]=z;
#pragma unroll
    for (int ks = 0; ks < 8; ++ks) {
        bf16x8 bfrag = *(const bf16x8*)(&Xt[wv*16 + col][ks*32 + quad*8]);
#pragma unroll
        for (int mb = 0; mb < 4; ++mb) {
            bf16x8 afrag = *(const bf16x8*)(&Wt[mb*16 + col][ks*32 + quad*8]);
            acc[mb] = MFMA16(afrag, bfrag, acc[mb]);
        }
    }
    int which = mt >> 3, h = mt & 7;
    if (which < 2) {
        float s = 0.f;
#pragma unroll
        for (int mb = 0; mb < 4; ++mb)
#pragma unroll
            for (int r = 0; r < 4; ++r) s += acc[mb][r] * acc[mb][r];
        s += __shfl_xor(s, 16);
        s += __shfl_xor(s, 32);
        float inv = 1.f / fmaxf(sqrtf(s), 1e-12f);
        if (which == 0) inv *= SCALE_LOG2E;   // fold softmax scale into Q
        u16* dst = (which == 0 ? Qn : Kn) + (((size_t)b * HEADS_ + h) * N_ + n) * DH_;
#pragma unroll
        for (int mb = 0; mb < 4; ++mb) {
            uint2 o;
            o.x = cvtpk(acc[mb][0] * inv, acc[mb][1] * inv);
            o.y = cvtpk(acc[mb][2] * inv, acc[mb][3] * inv);
            *(uint2*)(dst + mb*16 + quad*4) = o;
        }
    } else {
        u16* dst = Vt + ((size_t)b * HEADS_ + h) * (size_t)DH_ * N_;
#pragma unroll
        for (int mb = 0; mb < 4; ++mb)
#pragma unroll
            for (int r = 0; r < 4; ++r)
                dst[(size_t)(mb*16 + quad*4 + r) * N_ + n] = f2bf(acc[mb][r]);
    }
}

// ---------------- Kernel 1: QKV GEMM, mt-paired (Xt staged ONCE per 2 W-tiles) ----
// grid (12, 36, 4): block handles mt0 and mt0+12, halving block count and
// amortizing the X-tile stage over 2x the MFMA work.
__global__ __launch_bounds__(256) void k_qkv(const u16* __restrict__ w_qkv,
                                             const u16* __restrict__ xT,
                                             u16* __restrict__ Qn,
                                             u16* __restrict__ Kn,
                                             u16* __restrict__ Vt) {
    __shared__ __align__(16) u16 Wt[64][264];
    __shared__ __align__(16) u16 Xt[64][264];
    int mt0 = blockIdx.x, nt = blockIdx.y, b = blockIdx.z;
    int tid = threadIdx.x;
    int wv = tid >> 6, lane = tid & 63;
    int col = lane & 15, quad = lane >> 4;
    const u16* xtile = xT + ((size_t)b * N_ + nt*64) * C_;
    const u16* wtile0 = w_qkv + (size_t)(mt0 * 64) * C_;
#pragma unroll
    for (int p = 0; p < 8; ++p) {
        int c = p * 256 + tid;
        int row = c >> 5, seg = c & 31;
        *(uint4*)(&Wt[row][seg*8]) = *(const uint4*)(wtile0 + (size_t)row * C_ + seg*8);
        *(uint4*)(&Xt[row][seg*8]) = *(const uint4*)(xtile + (size_t)row * C_ + seg*8);
    }
    __syncthreads();
    int n = nt * 64 + wv * 16 + col;
    qkv_tile(Wt, Xt, wv, col, quad, n, b, mt0, Qn, Kn, Vt);
    __syncthreads();
    const u16* wtile1 = w_qkv + (size_t)((mt0 + 12) * 64) * C_;
#pragma unroll
    for (int p = 0; p < 8; ++p) {
        int c = p * 256 + tid;
        int row = c >> 5, seg = c & 31;
        *(uint4*)(&Wt[row][seg*8]) = *(const uint4*)(wtile1 + (size_t)row * C_ + seg*8);
    }
    __syncthreads();
    qkv_tile(Wt, Xt, wv, col, quad, n, b, mt0 + 12, Qn, Kn, Vt);
}

// store one 32-d block of O (already cvt/swap'd to contiguous groups)
__device__ __forceinline__ void store_o32(const f32x16 O, u16* dst, int hi) {
    unsigned c0 = cvtpk(O[0], O[1]),  c1 = cvtpk(O[2], O[3]);
    unsigned c2 = cvtpk(O[4], O[5]),  c3 = cvtpk(O[6], O[7]);
    unsigned c4 = cvtpk(O[8], O[9]),  c5 = cvtpk(O[10], O[11]);
    unsigned c6 = cvtpk(O[12], O[13]), c7 = cvtpk(O[14], O[15]);
    pl32swap(c0, c2); pl32swap(c1, c3);
    pl32swap(c4, c6); pl32swap(c5, c7);
    uint4 w0; w0.x = c0; w0.y = c1; w0.z = c2; w0.w = c3;
    uint4 w1; w1.x = c4; w1.y = c5; w1.z = c6; w1.w = c7;
    *(uint4*)(dst + hi*8)      = w0;
    *(uint4*)(dst + 16 + hi*8) = w1;
}

// build the two P bf16 B-frags for one 32-key half from 16 exp'd scores
#define SM_PACK(S, PF0, PF1, LSUM)                                              \
    {                                                                           \
        _Pragma("unroll")                                                       \
        for (int i = 0; i < 16; ++i) S[i] = fexp2(S[i]);                        \
        LSUM += ( ((S[0]+S[1])+(S[2]+S[3])) + ((S[4]+S[5])+(S[6]+S[7])) )       \
              + ( ((S[8]+S[9])+(S[10]+S[11])) + ((S[12]+S[13])+(S[14]+S[15])) );\
        unsigned c0 = cvtpk(S[0], S[1]),  c1 = cvtpk(S[2], S[3]);               \
        unsigned c2 = cvtpk(S[4], S[5]),  c3 = cvtpk(S[6], S[7]);               \
        unsigned c4 = cvtpk(S[8], S[9]),  c5 = cvtpk(S[10], S[11]);             \
        unsigned c6 = cvtpk(S[12], S[13]), c7 = cvtpk(S[14], S[15]);            \
        pl32swap(c0, c2); pl32swap(c1, c3);                                     \
        pl32swap(c4, c6); pl32swap(c5, c7);                                     \
        PF0.u[0] = c0; PF0.u[1] = c1; PF0.u[2] = c2; PF0.u[3] = c3;             \
        PF1.u[0] = c4; PF1.u[1] = c5; PF1.u[2] = c6; PF1.u[3] = c7;             \
    }

// ---------------- Kernel 2a: flash attention, 4-way K-split, 32x32 swapped-QK ----
// R9-best config: double-buffered K/V LDS, one barrier/iter, 2304 blocks
// (9/CU residency), single accO chains, VGPR 84. Do not perturb (R10 lesson).
__global__ __launch_bounds__(256) void k_attn_split(const u16* __restrict__ Qn,
                                                    const u16* __restrict__ Kn,
                                                    const u16* __restrict__ Vt,
                                                    u16* __restrict__ Opb,
                                                    float* __restrict__ lp) {
    __shared__ __align__(16) u16 Kt[2][64][72];
    __shared__ __align__(16) u16 Vtl[2][64][72];
    int head_lin = blockIdx.x & 31;                 // head -> XCD pinning
    int rest = blockIdx.x >> 5;                     // 0..71
    int qt = rest % 18;
    int ksplit = rest / 18;                         // 0..3
    int b = head_lin >> 3, h = head_lin & 7;
    int tid = threadIdx.x;
    int wv = tid >> 6, lane = tid & 63;
    int q32 = lane & 31, hi = lane >> 5;
    size_t head = (size_t)b * HEADS_ + h;
    const u16* Qh = Qn + head * (size_t)N_ * DH_;
    const u16* Kh = Kn + head * (size_t)N_ * DH_ + (size_t)ksplit * 576 * DH_;
    const u16* Vh = Vt + head * (size_t)DH_ * N_;
    int q0 = qt * 128 + wv * 32;
    bf16x8 qf[4];
#pragma unroll
    for (int ds = 0; ds < 4; ++ds)
        qf[ds] = *(const bf16x8*)(Qh + (size_t)(q0 + q32) * DH_ + ds*16 + hi*8);
    // opaque zero vector: stays live across the loop, never re-materialized
    float z0 = 0.f;
    asm volatile("" : "+v"(z0));
    f32x16 zv;
#pragma unroll
    for (int i = 0; i < 16; ++i) zv[i] = z0;
    f32x16 accO0 = zv, accO1 = zv;
    float lsum = 0.f;
    int srow = tid >> 3, sseg = tid & 7;
    const u16* ksrc0 = Kh + (size_t)tid * 8;
    const u16* vsrc0 = Vh + (size_t)srow * N_ + ksplit * 576 + sseg * 8;

    uint4 k0 = *(const uint4*)(ksrc0);
    uint4 k1 = *(const uint4*)(ksrc0 + 2048);
    uint4 v0 = *(const uint4*)(vsrc0);
    uint4 v1 = *(const uint4*)(vsrc0 + (size_t)32 * N_);
    *(uint4*)(&Kt[0][srow][sseg*8])       = k0;
    *(uint4*)(&Kt[0][32 + srow][sseg*8])  = k1;
    *(uint4*)(&Vtl[0][srow][sseg*8])      = v0;
    *(uint4*)(&Vtl[0][32 + srow][sseg*8]) = v1;
    const u16* kp = ksrc0 + 4096;                   // next K-tile (8KB stride)
    const u16* vp = vsrc0 + 64;                     // next V-tile (64-key stride)
    int cur = 0;

    for (int kt = 0; kt < 9; ++kt) {
        __syncthreads();
        // prefetch next tile (kt=8 over-reads <=8KB into workspace; dead buffer)
        k0 = *(const uint4*)(kp);
        k1 = *(const uint4*)(kp + 2048);
        v0 = *(const uint4*)(vp);
        v1 = *(const uint4*)(vp + (size_t)32 * N_);
        kp += 4096; vp += 64;
        const u16* kb0 = &Kt[cur][q32][hi*8];
        const u16* kb1 = kb0 + 32*72;
        const u16* vb0 = &Vtl[cur][q32][hi*8];
        const u16* vb1 = vb0 + 32*72;
        // ---- QK^T both key-halves (MFMA cluster) ----
        f32x16 s0, s1;
        __builtin_amdgcn_s_setprio(1);
        s0 = MFMA32(*(const bf16x8*)(kb0),      qf[0], zv);
        s0 = MFMA32(*(const bf16x8*)(kb0 + 16), qf[1], s0);
        s0 = MFMA32(*(const bf16x8*)(kb0 + 32), qf[2], s0);
        s0 = MFMA32(*(const bf16x8*)(kb0 + 48), qf[3], s0);
        s1 = MFMA32(*(const bf16x8*)(kb1),      qf[0], zv);
        s1 = MFMA32(*(const bf16x8*)(kb1 + 16), qf[1], s1);
        s1 = MFMA32(*(const bf16x8*)(kb1 + 32), qf[2], s1);
        s1 = MFMA32(*(const bf16x8*)(kb1 + 48), qf[3], s1);
        __builtin_amdgcn_s_setprio(0);
        // ---- softmax half 0 (VALU) ----
        union { unsigned u[4]; bf16x8 v; } pfA, pfB, pfC, pfD;
        SM_PACK(s0, pfA, pfB, lsum)
        // ---- PV half 0 (keys 0..31) ----
        __builtin_amdgcn_s_setprio(1);
        accO0 = MFMA32(*(const bf16x8*)(vb0),      pfA.v, accO0);
        accO1 = MFMA32(*(const bf16x8*)(vb1),      pfA.v, accO1);
        accO0 = MFMA32(*(const bf16x8*)(vb0 + 16), pfB.v, accO0);
        accO1 = MFMA32(*(const bf16x8*)(vb1 + 16), pfB.v, accO1);
        __builtin_amdgcn_s_setprio(0);
        // ---- softmax half 1 (VALU) ----
        SM_PACK(s1, pfC, pfD, lsum)
        // ---- PV half 1 (keys 32..63) ----
        __builtin_amdgcn_s_setprio(1);
        accO0 = MFMA32(*(const bf16x8*)(vb0 + 32), pfC.v, accO0);
        accO1 = MFMA32(*(const bf16x8*)(vb1 + 32), pfC.v, accO1);
        accO0 = MFMA32(*(const bf16x8*)(vb0 + 48), pfD.v, accO0);
        accO1 = MFMA32(*(const bf16x8*)(vb1 + 48), pfD.v, accO1);
        __builtin_amdgcn_s_setprio(0);
        // ---- stage next tile into the other buffer ----
        {
            u16 (*Ktn_)[72] = Kt[cur ^ 1];
            u16 (*Vtn_)[72] = Vtl[cur ^ 1];
            *(uint4*)(&Ktn_[srow][sseg*8])      = k0;
            *(uint4*)(&Ktn_[32 + srow][sseg*8]) = k1;
            *(uint4*)(&Vtn_[srow][sseg*8])      = v0;
            *(uint4*)(&Vtn_[32 + srow][sseg*8]) = v1;
        }
        cur ^= 1;
    }
    lsum += __shfl_xor(lsum, 32);
    u16* dst = Opb + (((size_t)ksplit * B_ + b) * N_ + q0 + q32) * INNER_ + h * DH_;
    store_o32(accO0, dst, hi);
    store_o32(accO1, dst + 32, hi);
    if (hi == 0) {
        size_t lbase = (((size_t)ksplit * B_ + b) * HEADS_ + h) * N_;
        lp[lbase + q0 + q32] = lsum;
    }
}

// ---------------- Kernel 2c: combine 4 bf16 partials -> AO bf16 ----------------
// XCD-pinned (blockIdx&31 matches producer). uint4 (8 bf16) per thread.
__global__ __launch_bounds__(256) void k_comb(const u16* __restrict__ Opb,
                                              const float* __restrict__ lp,
                                              u16* __restrict__ AO) {
    int head_lin = blockIdx.x & 31;               // same pinning as attn
    int chunk = blockIdx.x >> 5;                  // 0..71
    int b = head_lin >> 3, h = head_lin & 7;
    int j = chunk * 256 + threadIdx.x;            // 0..18431 per (b,h)
    int n = j >> 3;                               // 0..2303
    int i8 = j & 7;                               // uint4 within 64-d head slice
    size_t g = ((size_t)b * N_ + n) * 64 + h * 8 + i8;   // uint4 units
    float l = 0.f;
#pragma unroll
    for (int s = 0; s < 4; ++s)
        l += lp[(((size_t)s * B_ + b) * HEADS_ + h) * N_ + n];
    float s0=0.f,s1=0.f,s2=0.f,s3=0.f,s4=0.f,s5=0.f,s6=0.f,s7=0.f;
#pragma unroll
    for (int s = 0; s < 4; ++s) {
        uint4 p = ((const uint4*)Opb)[g + (size_t)s * 589824];
        bfacc(p.x, s0, s1); bfacc(p.y, s2, s3);
        bfacc(p.z, s4, s5); bfacc(p.w, s6, s7);
    }
    float inv = 1.f / l;
    uint4 o;
    o.x = cvtpk(s0*inv, s1*inv); o.y = cvtpk(s2*inv, s3*inv);
    o.z = cvtpk(s4*inv, s5*inv); o.w = cvtpk(s6*inv, s7*inv);
    ((uint4*)AO)[g] = o;
}

// ---------------- Kernel 2b: fallback single-pass attention ----------------
__global__ __launch_bounds__(256) void k_attn(const u16* __restrict__ Qn,
                                              const u16* __restrict__ Kn,
                                              const u16* __restrict__ Vt,
                                              u16* __restrict__ AO) {
    __shared__ __align__(16) u16 Kt[64][72];
    __shared__ __align__(16) u16 Vtl[64][72];
    __shared__ __align__(16) u16 plds[4][32][72];
    int head_lin = blockIdx.x & 31;
    int qt = blockIdx.x >> 5;
    int b = head_lin >> 3, h = head_lin & 7;
    int tid = threadIdx.x;
    int wv = tid >> 6, lane = tid & 63;
    int col = lane & 15, quad = lane >> 4;
    size_t head = (size_t)b * HEADS_ + h;
    const u16* Qh = Qn + head * (size_t)N_ * DH_;
    const u16* Kh = Kn + head * (size_t)N_ * DH_;
    const u16* Vh = Vt + head * (size_t)DH_ * N_;
    int q0 = qt * 128 + wv * 32;
    bf16x8 qfA0 = *(const bf16x8*)(Qh + (size_t)(q0 + col) * DH_ + quad*8);
    bf16x8 qfA1 = *(const bf16x8*)(Qh + (size_t)(q0 + col) * DH_ + 32 + quad*8);
    bf16x8 qfB0 = *(const bf16x8*)(Qh + (size_t)(q0 + 16 + col) * DH_ + quad*8);
    bf16x8 qfB1 = *(const bf16x8*)(Qh + (size_t)(q0 + 16 + col) * DH_ + 32 + quad*8);
    f32x4 z = {0.f, 0.f, 0.f, 0.f};
    f32x4 OA[4], OB[4];
#pragma unroll
    for (int i = 0; i < 4; ++i) { OA[i] = z; OB[i] = z; }
    float lA = 0.f, lB = 0.f;
    int srow = tid >> 3, sseg = tid & 7;
    const u16* ksrc0 = Kh + (size_t)tid * 8;
    const u16* vsrc0 = Vh + (size_t)srow * N_ + sseg * 8;
    uint4 k0 = *(const uint4*)(ksrc0);
    uint4 k1 = *(const uint4*)(ksrc0 + 2048);
    uint4 v0 = *(const uint4*)(vsrc0);
    uint4 v1 = *(const uint4*)(vsrc0 + (size_t)32 * N_);
    for (int kt = 0; kt < N_/64; ++kt) {
        *(uint4*)(&Kt[srow][sseg*8])      = k0;
        *(uint4*)(&Kt[32 + srow][sseg*8]) = k1;
        *(uint4*)(&Vtl[srow][sseg*8])      = v0;
        *(uint4*)(&Vtl[32 + srow][sseg*8]) = v1;
        __syncthreads();
        int ktn = kt + 1 < N_/64 ? kt + 1 : kt;
        k0 = *(const uint4*)(ksrc0 + (size_t)ktn * 4096);
        k1 = *(const uint4*)(ksrc0 + (size_t)ktn * 4096 + 2048);
        v0 = *(const uint4*)(vsrc0 + ktn * 64);
        v1 = *(const uint4*)(vsrc0 + (size_t)32 * N_ + ktn * 64);
        float rsA = 0.f, rsB = 0.f;
#pragma unroll
        for (int nb = 0; nb < 4; ++nb) {
            bf16x8 kf0 = *(const bf16x8*)(&Kt[nb*16 + col][quad*8]);
            bf16x8 kf1 = *(const bf16x8*)(&Kt[nb*16 + col][32 + quad*8]);
            f32x4 a = MFMA16(kf0, qfA0, z);
            a = MFMA16(kf1, qfA1, a);
            f32x4 c = MFMA16(kf0, qfB0, z);
            c = MFMA16(kf1, qfB1, c);
            float a0 = fexp2(a[0]);
            float a1 = fexp2(a[1]);
            float a2 = fexp2(a[2]);
            float a3 = fexp2(a[3]);
            float c0 = fexp2(c[0]);
            float c1 = fexp2(c[1]);
            float c2 = fexp2(c[2]);
            float c3 = fexp2(c[3]);
            rsA += (a0 + a1) + (a2 + a3);
            rsB += (c0 + c1) + (c2 + c3);
            uint2 wA, wB;
            wA.x = cvtpk(a0, a1); wA.y = cvtpk(a2, a3);
            wB.x = cvtpk(c0, c1); wB.y = cvtpk(c2, c3);
            *(uint2*)(&plds[wv][col][nb*16 + quad*4]) = wA;
            *(uint2*)(&plds[wv][16 + col][nb*16 + quad*4]) = wB;
        }
        lA += rsA; lB += rsB;
        __asm__ volatile("" ::: "memory");
#pragma unroll
        for (int ks = 0; ks < 2; ++ks) {
            bf16x8 pfA = *(const bf16x8*)(&plds[wv][col][ks*32 + quad*8]);
            bf16x8 pfB = *(const bf16x8*)(&plds[wv][16 + col][ks*32 + quad*8]);
#pragma unroll
            for (int nb = 0; nb < 4; ++nb) {
                bf16x8 vf = *(const bf16x8*)(&Vtl[nb*16 + col][ks*32 + quad*8]);
                OA[nb] = MFMA16(vf, pfA, OA[nb]);
                OB[nb] = MFMA16(vf, pfB, OB[nb]);
            }
        }
        __asm__ volatile("" ::: "memory");
        __syncthreads();
    }
    lA += __shfl_xor(lA, 16); lA += __shfl_xor(lA, 32);
    lB += __shfl_xor(lB, 16); lB += __shfl_xor(lB, 32);
    float linvA = 1.f / lA, linvB = 1.f / lB;
    u16* dstA = AO + ((size_t)b * N_ + q0 + col) * INNER_ + h * DH_;
    u16* dstB = AO + ((size_t)b * N_ + q0 + 16 + col) * INNER_ + h * DH_;
#pragma unroll
    for (int nb = 0; nb < 4; ++nb) {
        uint2 wA, wB;
        wA.x = cvtpk(OA[nb][0] * linvA, OA[nb][1] * linvA);
        wA.y = cvtpk(OA[nb][2] * linvA, OA[nb][3] * linvA);
        wB.x = cvtpk(OB[nb][0] * linvB, OB[nb][1] * linvB);
        wB.y = cvtpk(OB[nb][2] * linvB, OB[nb][3] * linvB);
        *(uint2*)(dstA + nb*16 + quad*4) = wA;
        *(uint2*)(dstB + nb*16 + quad*4) = wB;
    }
}

// ---------------- Kernel 3: output projection (LDS-staged) + bias ----------------
__global__ __launch_bounds__(256) void k_proj(const u16* __restrict__ w_out,
                                              const float* __restrict__ b_out,
                                              const u16* __restrict__ AO,
                                              float* __restrict__ out) {
    __shared__ __align__(16) u16 Wt[64][264];
    __shared__ __align__(16) u16 At[64][264];
    int mt = blockIdx.x, nt = blockIdx.y, b = blockIdx.z;
    int tid = threadIdx.x;
    int wv = tid >> 6, lane = tid & 63;
    int col = lane & 15, quad = lane >> 4;
    int o0b = mt * 64;
    const u16* wtile = w_out + (size_t)o0b * INNER_;
    const u16* atile = AO + ((size_t)b * N_ + nt*64) * INNER_;
    f32x4 z = {0.f, 0.f, 0.f, 0.f};
    f32x4 acc[4]; acc[0]=z; acc[1]=z; acc[2]=z; acc[3]=z;
#pragma unroll
    for (int half = 0; half < 2; ++half) {
        if (half) __syncthreads();
#pragma unroll
        for (int p = 0; p < 8; ++p) {
            int c = p * 256 + tid;
            int row = c >> 5, seg = c & 31;
            *(uint4*)(&Wt[row][seg*8]) =
                *(const uint4*)(wtile + (size_t)row * INNER_ + half*256 + seg*8);
            *(uint4*)(&At[row][seg*8]) =
                *(const uint4*)(atile + (size_t)row * INNER_ + half*256 + seg*8);
        }
        __syncthreads();
#pragma unroll
        for (int ks = 0; ks < 8; ++ks) {
            bf16x8 af = *(const bf16x8*)(&Wt[wv*16 + col][ks*32 + quad*8]);
#pragma unroll
            for (int nb = 0; nb < 4; ++nb) {
                bf16x8 bfv = *(const bf16x8*)(&At[nb*16 + col][ks*32 + quad*8]);
                acc[nb] = MFMA16(af, bfv, acc[nb]);
            }
        }
    }
    int o0 = o0b + wv * 16;
    float bias[4];
#pragma unroll
    for (int r = 0; r < 4; ++r) bias[r] = b_out[o0 + quad*4 + r];
    float* dst = out + ((size_t)b * C_ + o0) * N_ + nt*64;
#pragma unroll
    for (int nb = 0; nb < 4; ++nb)
#pragma unroll
        for (int r = 0; r < 4; ++r)
            dst[(size_t)(quad*4 + r) * N_ + nb*16 + col] = acc[nb][r] + bias[r];
}

// ---------------- launch ----------------
extern "C" void kernel_launch(void* const* d_in, const int* in_sizes, int n_in,
                              void* d_out, int out_size, void* d_ws, size_t ws_size,
                              hipStream_t stream) {
    const float* x     = (const float*)d_in[0];
    const float* w_qkv = (const float*)d_in[1];
    const float* w_out = (const float*)d_in[2];
    const float* b_out = (const float*)d_in[3];
    float* out = (float*)d_out;

    char* ws = (char*)d_ws;
    u16* xT  = (u16*)(ws);                 // dead after k_qkv; lp reuses this region
    u16* Qn  = (u16*)(ws + 4718592);
    u16* Kn  = (u16*)(ws + 14155776);
    u16* Vt  = (u16*)(ws + 23592960);
    u16* AO  = (u16*)(ws + 33030144);
    u16* wqb = (u16*)(ws + 42467328);
    u16* wob = (u16*)(ws + 43253760);
    u16* Opb = (u16*)(ws + 43515904);      // 4 x 9,437,184 B bf16 partials
    float* lp = (float*)(ws + 1179648);    // 4 x 294,912 B f32 row sums (dead xT region)
    const size_t need = 81854464;

    hipLaunchKernelGGL(k_prep, dim3(1088), dim3(256), 0, stream, x, xT, w_qkv, wqb, w_out, wob);
    hipLaunchKernelGGL(k_qkv,  dim3(12, N_/64, B_), dim3(256), 0, stream, wqb, xT, Qn, Kn, Vt);
    if (ws_size >= need) {
        hipLaunchKernelGGL(k_attn_split, dim3(2304), dim3(256), 0, stream, Qn, Kn, Vt, Opb, lp);
        hipLaunchKernelGGL(k_comb, dim3(2304), dim3(256), 0, stream, Opb, lp, AO);
    } else {
        hipLaunchKernelGGL(k_attn, dim3((N_/128) * 32), dim3(256), 0, stream, Qn, Kn, Vt, AO);
    }
    hipLaunchKernelGGL(k_proj, dim3(C_/64, N_/64, B_), dim3(256), 0, stream, wob, b_out, AO, out);
}